// Round 5
// baseline (118.425 us; speedup 1.0000x reference)
//
#include <hip/hip_runtime.h>
#include <hip/hip_bf16.h>

// flex_conv via MFMA + async LDS staging (global_load_lds), RB=2 for residency.
// t[k=ic*4+d][pixel]: t_d = ctr_d*Xs - PX_d (d<3), t_3 = Xs
// out[o][pixel] = Kmat[o][k] . t[k][pixel]  -> 16x16x32 bf16 MFMA
// (A[m=p][k=c*8+..], B[k][n=p], D row=c*4+r col=p — validated R2-R4).
//
// Block = 256 thr (4 waves) owns a 64-col x RB=2-row output tile.
// Stage 19 planes (16 x + 3 pts) x 4 input rows x 68 cols into LDS via
// __builtin_amdgcn_global_load_lds width=16: chunk cid lands at LDS byte
// cid*16 (wave-uniform base + lane*16 — the HW-required layout), which
// equals row-major [plane*TR+rr][col] with LC=68.
// 20.7 KB LDS -> 7 blocks/CU resident; grid 3968 blocks = 15.5 blocks/CU work.

#define HH 64
#define WW 512
#define HP 62
#define WP 510
#define IC 16
#define OC 32
#define BS 16
#define RB 2            // output rows per block
#define TR (RB + 2)     // staged input rows = 4
#define TC 64           // output cols per block
#define LC 68           // LDS row length in floats (= CPR*4)
#define NPL 19          // planes staged: 16 x + 3 pts
#define CPR 17          // float4 chunks per row
#define NROWS (NPL * TR)        // 76
#define NCHUNK (NROWS * CPR)    // 1292

typedef __attribute__((ext_vector_type(8))) short short8;
typedef __attribute__((ext_vector_type(4))) float f32x4;

static __device__ __forceinline__ short f2bf(float f) {
    union { __hip_bfloat16 h; short s; } u;
    u.h = __float2bfloat16(f);
    return u.s;
}

__global__ __launch_bounds__(256) void flex_conv_async(
    const float* __restrict__ x, const float* __restrict__ kern,
    const float* __restrict__ pts, float* __restrict__ out)
{
    __shared__ float lds[NPL * TR * LC];   // 5168 floats = 20672 B

    const int tid = threadIdx.x;
    const int j0 = blockIdx.x * TC;
    const int i0 = blockIdx.y * RB;        // 0,2,..,60 (exact, no tail)
    const int b = blockIdx.z;

    const float* xb = x + (size_t)b * IC * HH * WW;
    const float* pb = pts + (size_t)b * 3 * HH * WW;

    // ---- async staging: 1292 16B chunks over 256 threads, direct to LDS ----
    #pragma unroll
    for (int rnd = 0; rnd < 6; ++rnd) {
        const int cid = tid + rnd * 256;
        if (cid < NCHUNK) {
            const int row = cid / CPR;           // 0..75 = plane*TR + rr
            const int chunk = cid - row * CPR;   // 0..16
            const int plane = row >> 2;          // /TR, 0..18
            const int rr = row & (TR - 1);
            const float* base = (plane < IC)
                ? (xb + (size_t)plane * HH * WW)
                : (pb + (size_t)(plane - IC) * HH * WW);
            int gcol = j0 + chunk * 4;
            if (gcol > WW - 4) gcol = WW - 4;    // clamp; garbage lands in unused cells
            const float* g = base + (size_t)(i0 + rr) * WW + gcol;
            __builtin_amdgcn_global_load_lds(
                (const __attribute__((address_space(1))) void*)g,
                (__attribute__((address_space(3))) void*)(lds + (size_t)cid * 4),
                16, 0, 0);
        }
    }

    // ---- A fragments (independent of LDS; overlaps staging latency) ----
    const int lane = tid & 63;
    const int wave = tid >> 6;
    const int p = lane & 15;
    const int c = lane >> 4;
    const int tc = wave * 16 + p;        // tile col of this lane's pixel

    short8 a0lo, a0hi, a1lo, a1hi;
    {
        const float4* k0v = (const float4*)(kern + (size_t)p * 64 + c * 8);
        const float4* k1v = (const float4*)(kern + (size_t)(16 + p) * 64 + c * 8);
        float4 v0a = k0v[0], v0b = k0v[1], v0c = k0v[8], v0d = k0v[9];
        float4 v1a = k1v[0], v1b = k1v[1], v1c = k1v[8], v1d = k1v[9];
        a0lo[0]=f2bf(v0a.x); a0lo[1]=f2bf(v0a.y); a0lo[2]=f2bf(v0a.z); a0lo[3]=f2bf(v0a.w);
        a0lo[4]=f2bf(v0b.x); a0lo[5]=f2bf(v0b.y); a0lo[6]=f2bf(v0b.z); a0lo[7]=f2bf(v0b.w);
        a0hi[0]=f2bf(v0c.x); a0hi[1]=f2bf(v0c.y); a0hi[2]=f2bf(v0c.z); a0hi[3]=f2bf(v0c.w);
        a0hi[4]=f2bf(v0d.x); a0hi[5]=f2bf(v0d.y); a0hi[6]=f2bf(v0d.z); a0hi[7]=f2bf(v0d.w);
        a1lo[0]=f2bf(v1a.x); a1lo[1]=f2bf(v1a.y); a1lo[2]=f2bf(v1a.z); a1lo[3]=f2bf(v1a.w);
        a1lo[4]=f2bf(v1b.x); a1lo[5]=f2bf(v1b.y); a1lo[6]=f2bf(v1b.z); a1lo[7]=f2bf(v1b.w);
        a1hi[0]=f2bf(v1c.x); a1hi[1]=f2bf(v1c.y); a1hi[2]=f2bf(v1c.z); a1hi[3]=f2bf(v1c.w);
        a1hi[4]=f2bf(v1d.x); a1hi[5]=f2bf(v1d.y); a1hi[6]=f2bf(v1d.z); a1hi[7]=f2bf(v1d.w);
    }

    __syncthreads();

    // ---- window partials from LDS ----
    float xs[4][RB], px0[4][RB], px1[4][RB], px2[4][RB];
    #pragma unroll
    for (int t = 0; t < 4; ++t)
        #pragma unroll
        for (int q = 0; q < RB; ++q) { xs[t][q]=0.f; px0[t][q]=0.f; px1[t][q]=0.f; px2[t][q]=0.f; }
    float c0v[RB], c1v[RB], c2v[RB];

    #pragma unroll
    for (int rr = 0; rr < TR; ++rr) {
        const float* lp0 = &lds[(IC * TR + rr) * LC + tc];        // pts planes
        const float* lp1 = &lds[((IC + 1) * TR + rr) * LC + tc];
        const float* lp2 = &lds[((IC + 2) * TR + rr) * LC + tc];
        const float pa0 = lp0[0], pm0 = lp0[1], pz0 = lp0[2];
        const float pa1 = lp1[0], pm1 = lp1[1], pz1 = lp1[2];
        const float pa2 = lp2[0], pm2 = lp2[1], pz2 = lp2[2];
        if (rr >= 1 && rr <= RB) { c0v[rr-1] = pm0; c1v[rr-1] = pm1; c2v[rr-1] = pm2; }
        #pragma unroll
        for (int t = 0; t < 4; ++t) {
            const int ic = (t >> 1) * 8 + 2 * c + (t & 1);
            const float* lx = &lds[(ic * TR + rr) * LC + tc];
            const float x0 = lx[0], x1 = lx[1], x2 = lx[2];
            const float rsx = x0 + x1 + x2;
            float r0 = pa0 * x0; r0 = fmaf(pm0, x1, r0); r0 = fmaf(pz0, x2, r0);
            float r1 = pa1 * x0; r1 = fmaf(pm1, x1, r1); r1 = fmaf(pz1, x2, r1);
            float r2 = pa2 * x0; r2 = fmaf(pm2, x1, r2); r2 = fmaf(pz2, x2, r2);
            #pragma unroll
            for (int q = 0; q < RB; ++q) {
                if (rr >= q && rr <= q + 2) {
                    xs[t][q] += rsx; px0[t][q] += r0; px1[t][q] += r1; px2[t][q] += r2;
                }
            }
        }
    }

    // ---- per output row: B fragments -> MFMA -> store ----
    const int j = j0 + tc;
    #pragma unroll
    for (int q = 0; q < RB; ++q) {
        short8 blo, bhi;
        #pragma unroll
        for (int t = 0; t < 4; ++t) {
            const short t0 = f2bf(fmaf(c0v[q], xs[t][q], -px0[t][q]));
            const short t1 = f2bf(fmaf(c1v[q], xs[t][q], -px1[t][q]));
            const short t2 = f2bf(fmaf(c2v[q], xs[t][q], -px2[t][q]));
            const short t3 = f2bf(xs[t][q]);
            const int s = (t & 1) * 4;
            if (t < 2) { blo[s+0]=t0; blo[s+1]=t1; blo[s+2]=t2; blo[s+3]=t3; }
            else       { bhi[s+0]=t0; bhi[s+1]=t1; bhi[s+2]=t2; bhi[s+3]=t3; }
        }
        f32x4 acc0 = {0.f,0.f,0.f,0.f}, acc1 = {0.f,0.f,0.f,0.f};
        acc0 = __builtin_amdgcn_mfma_f32_16x16x32_bf16(a0lo, blo, acc0, 0, 0, 0);
        acc0 = __builtin_amdgcn_mfma_f32_16x16x32_bf16(a0hi, bhi, acc0, 0, 0, 0);
        acc1 = __builtin_amdgcn_mfma_f32_16x16x32_bf16(a1lo, blo, acc1, 0, 0, 0);
        acc1 = __builtin_amdgcn_mfma_f32_16x16x32_bf16(a1hi, bhi, acc1, 0, 0, 0);
        if (j < WP) {
            float* ob = out + (size_t)b * OC * HP * WP + (size_t)(i0 + q) * WP + j;
            #pragma unroll
            for (int r = 0; r < 4; ++r) {
                const int o = c * 4 + r;
                ob[(size_t)o * HP * WP]        = acc0[r];
                ob[(size_t)(o + 16) * HP * WP] = acc1[r];
            }
        }
    }
}

extern "C" void kernel_launch(void* const* d_in, const int* in_sizes, int n_in,
                              void* d_out, int out_size, void* d_ws, size_t ws_size,
                              hipStream_t stream)
{
    const float* x    = (const float*)d_in[0];
    const float* kern = (const float*)d_in[1];
    const float* pts  = (const float*)d_in[2];
    float* out = (float*)d_out;

    dim3 block(256, 1, 1);
    dim3 grid(WW / TC, HP / RB, BS);   // 8 x 31 x 16 = 3968 blocks
    flex_conv_async<<<grid, block, 0, stream>>>(x, kern, pts, out);
}

// Round 6
// 115.404 us; speedup vs baseline: 1.0262x; 1.0262x over previous
//
#include <hip/hip_runtime.h>
#include <hip/hip_bf16.h>

// flex_conv via MFMA + double-buffered async-LDS pipeline.
// t[k=ic*4+d][pixel]: t_d = ctr_d*Xs - PX_d (d<3), t_3 = Xs
// out[o][pixel] = Kmat[o][k] . t[k][pixel]  -> 16x16x32 bf16 MFMA
// (A[m=p][k=c*8+..], B[k][n=p], D row=c*4+r col=p — validated R2-R5).
//
// Block = 256 thr owns a 64-col strip and LOOPS over TPG=4 row-tiles
// (RB=4 output rows each), double-buffering: prefetch tile s+1 via
// global_load_lds right after the barrier, compute tile s from the other
// buffer. The next barrier's vmcnt(0) drain lands after a full compute
// phase -> stage latency hidden except on tile 0.
// TR=6 layout: x-read c-group stride = 2 planes = 816 floats = 16 mod 32
// banks -> 2-way conflicts only (free); pts reads broadcast (free).

#define HH 64
#define WW 512
#define HP 62
#define WP 510
#define IC 16
#define OC 32
#define BS 16
#define RB 4            // output rows per tile
#define TR (RB + 2)     // staged input rows = 6
#define TC 64           // output cols per block
#define LC 68           // LDS row length in floats (= CPR*4)
#define NPL 19          // planes staged: 16 x + 3 pts
#define CPR 17          // float4 chunks per row
#define NROWS (NPL * TR)        // 114
#define NCHUNK (NROWS * CPR)    // 1938
#define NRND 8                  // ceil(1938/256)
#define TPG 4                   // row-tiles per block
#define LDSZ (NPL * TR * LC)    // 7752 floats = 31008 B per buffer

typedef __attribute__((ext_vector_type(8))) short short8;
typedef __attribute__((ext_vector_type(4))) float f32x4;

static __device__ __forceinline__ short f2bf(float f) {
    union { __hip_bfloat16 h; short s; } u;
    u.h = __float2bfloat16(f);
    return u.s;
}

__global__ __launch_bounds__(256) void flex_conv_pipe(
    const float* __restrict__ x, const float* __restrict__ kern,
    const float* __restrict__ pts, float* __restrict__ out)
{
    __shared__ float lds[2][LDSZ];   // 62016 B -> 2 blocks/CU

    const int tid = threadIdx.x;
    const int j0 = blockIdx.x * TC;
    const int b  = blockIdx.z;
    const int t0 = blockIdx.y * TPG;   // first row-tile of this block

    const float* xb = x + (size_t)b * IC * HH * WW;
    const float* pb = pts + (size_t)b * 3 * HH * WW;

    // ---- per-round staging descriptors (row-tile independent) ----
    const float* gbase[NRND];
    bool act[NRND];
    #pragma unroll
    for (int rnd = 0; rnd < NRND; ++rnd) {
        const int cid = tid + rnd * 256;
        act[rnd] = (cid < NCHUNK);
        const int cc = act[rnd] ? cid : 0;
        const int row = cc / CPR;            // plane*TR + rr
        const int chunk = cc - row * CPR;
        const int plane = row / TR;
        const int rr = row - plane * TR;
        const float* base = (plane < IC)
            ? (xb + (size_t)plane * HH * WW)
            : (pb + (size_t)(plane - IC) * HH * WW);
        int gcol = j0 + chunk * 4;
        if (gcol > WW - 4) gcol = WW - 4;    // clamp; garbage lands in unused cols 64..67
        gbase[rnd] = base + (size_t)rr * WW + gcol;
    }

    // ---- stage tile 0 into buffer 0 ----
    {
        const int i00t = t0 * RB;
        const int i00 = (i00t > HP - RB) ? (HP - RB) : i00t;
        #pragma unroll
        for (int rnd = 0; rnd < NRND; ++rnd) {
            if (act[rnd]) {
                const float* g = gbase[rnd] + (size_t)i00 * WW;
                __builtin_amdgcn_global_load_lds(
                    (const __attribute__((address_space(1))) void*)g,
                    (__attribute__((address_space(3))) void*)(&lds[0][0] + (size_t)(tid + rnd * 256) * 4),
                    16, 0, 0);
            }
        }
    }

    // ---- A fragments (independent; overlaps tile-0 staging) ----
    const int lane = tid & 63;
    const int wave = tid >> 6;
    const int p = lane & 15;
    const int c = lane >> 4;
    const int tc = wave * 16 + p;

    short8 a0lo, a0hi, a1lo, a1hi;
    {
        const float4* k0v = (const float4*)(kern + (size_t)p * 64 + c * 8);
        const float4* k1v = (const float4*)(kern + (size_t)(16 + p) * 64 + c * 8);
        float4 v0a = k0v[0], v0b = k0v[1], v0c = k0v[8], v0d = k0v[9];
        float4 v1a = k1v[0], v1b = k1v[1], v1c = k1v[8], v1d = k1v[9];
        a0lo[0]=f2bf(v0a.x); a0lo[1]=f2bf(v0a.y); a0lo[2]=f2bf(v0a.z); a0lo[3]=f2bf(v0a.w);
        a0lo[4]=f2bf(v0b.x); a0lo[5]=f2bf(v0b.y); a0lo[6]=f2bf(v0b.z); a0lo[7]=f2bf(v0b.w);
        a0hi[0]=f2bf(v0c.x); a0hi[1]=f2bf(v0c.y); a0hi[2]=f2bf(v0c.z); a0hi[3]=f2bf(v0c.w);
        a0hi[4]=f2bf(v0d.x); a0hi[5]=f2bf(v0d.y); a0hi[6]=f2bf(v0d.z); a0hi[7]=f2bf(v0d.w);
        a1lo[0]=f2bf(v1a.x); a1lo[1]=f2bf(v1a.y); a1lo[2]=f2bf(v1a.z); a1lo[3]=f2bf(v1a.w);
        a1lo[4]=f2bf(v1b.x); a1lo[5]=f2bf(v1b.y); a1lo[6]=f2bf(v1b.z); a1lo[7]=f2bf(v1b.w);
        a1hi[0]=f2bf(v1c.x); a1hi[1]=f2bf(v1c.y); a1hi[2]=f2bf(v1c.z); a1hi[3]=f2bf(v1c.w);
        a1hi[4]=f2bf(v1d.x); a1hi[5]=f2bf(v1d.y); a1hi[6]=f2bf(v1d.z); a1hi[7]=f2bf(v1d.w);
    }

    const int j = j0 + tc;

    // ---- pipelined tile loop ----
    for (int s = 0; s < TPG; ++s) {
        __syncthreads();   // drains staging for tile s (vmcnt(0)) + guards buffer reuse

        // prefetch tile s+1 into the other buffer (async; drained by NEXT barrier)
        if (s + 1 < TPG) {
            const int i1t = (t0 + s + 1) * RB;
            const int i1 = (i1t > HP - RB) ? (HP - RB) : i1t;
            float* dst = &lds[(s + 1) & 1][0];
            #pragma unroll
            for (int rnd = 0; rnd < NRND; ++rnd) {
                if (act[rnd]) {
                    const float* g = gbase[rnd] + (size_t)i1 * WW;
                    __builtin_amdgcn_global_load_lds(
                        (const __attribute__((address_space(1))) void*)g,
                        (__attribute__((address_space(3))) void*)(dst + (size_t)(tid + rnd * 256) * 4),
                        16, 0, 0);
                }
            }
        }

        const int i0t = (t0 + s) * RB;
        const int i0 = (i0t > HP - RB) ? (HP - RB) : i0t;
        const float* ldsb = &lds[s & 1][0];

        // ---- window partials from LDS ----
        float xs[4][RB], px0[4][RB], px1[4][RB], px2[4][RB];
        #pragma unroll
        for (int t = 0; t < 4; ++t)
            #pragma unroll
            for (int q = 0; q < RB; ++q) { xs[t][q]=0.f; px0[t][q]=0.f; px1[t][q]=0.f; px2[t][q]=0.f; }
        float c0v[RB], c1v[RB], c2v[RB];

        #pragma unroll
        for (int rr = 0; rr < TR; ++rr) {
            const float* lp0 = &ldsb[(IC * TR + rr) * LC + tc];
            const float* lp1 = &ldsb[((IC + 1) * TR + rr) * LC + tc];
            const float* lp2 = &ldsb[((IC + 2) * TR + rr) * LC + tc];
            const float pa0 = lp0[0], pm0 = lp0[1], pz0 = lp0[2];
            const float pa1 = lp1[0], pm1 = lp1[1], pz1 = lp1[2];
            const float pa2 = lp2[0], pm2 = lp2[1], pz2 = lp2[2];
            if (rr >= 1 && rr <= RB) { c0v[rr-1] = pm0; c1v[rr-1] = pm1; c2v[rr-1] = pm2; }
            #pragma unroll
            for (int t = 0; t < 4; ++t) {
                const int ic = (t >> 1) * 8 + 2 * c + (t & 1);
                const float* lx = &ldsb[(ic * TR + rr) * LC + tc];
                const float x0 = lx[0], x1 = lx[1], x2 = lx[2];
                const float rsx = x0 + x1 + x2;
                float r0 = pa0 * x0; r0 = fmaf(pm0, x1, r0); r0 = fmaf(pz0, x2, r0);
                float r1 = pa1 * x0; r1 = fmaf(pm1, x1, r1); r1 = fmaf(pz1, x2, r1);
                float r2 = pa2 * x0; r2 = fmaf(pm2, x1, r2); r2 = fmaf(pz2, x2, r2);
                #pragma unroll
                for (int q = 0; q < RB; ++q) {
                    if (rr >= q && rr <= q + 2) {
                        xs[t][q] += rsx; px0[t][q] += r0; px1[t][q] += r1; px2[t][q] += r2;
                    }
                }
            }
        }

        // ---- per output row: B fragments -> MFMA -> store ----
        #pragma unroll
        for (int q = 0; q < RB; ++q) {
            short8 blo, bhi;
            #pragma unroll
            for (int t = 0; t < 4; ++t) {
                const short e0 = f2bf(fmaf(c0v[q], xs[t][q], -px0[t][q]));
                const short e1 = f2bf(fmaf(c1v[q], xs[t][q], -px1[t][q]));
                const short e2 = f2bf(fmaf(c2v[q], xs[t][q], -px2[t][q]));
                const short e3 = f2bf(xs[t][q]);
                const int sl = (t & 1) * 4;
                if (t < 2) { blo[sl+0]=e0; blo[sl+1]=e1; blo[sl+2]=e2; blo[sl+3]=e3; }
                else       { bhi[sl+0]=e0; bhi[sl+1]=e1; bhi[sl+2]=e2; bhi[sl+3]=e3; }
            }
            f32x4 acc0 = {0.f,0.f,0.f,0.f}, acc1 = {0.f,0.f,0.f,0.f};
            acc0 = __builtin_amdgcn_mfma_f32_16x16x32_bf16(a0lo, blo, acc0, 0, 0, 0);
            acc0 = __builtin_amdgcn_mfma_f32_16x16x32_bf16(a0hi, bhi, acc0, 0, 0, 0);
            acc1 = __builtin_amdgcn_mfma_f32_16x16x32_bf16(a1lo, blo, acc1, 0, 0, 0);
            acc1 = __builtin_amdgcn_mfma_f32_16x16x32_bf16(a1hi, bhi, acc1, 0, 0, 0);
            if (j < WP) {
                float* ob = out + (size_t)b * OC * HP * WP + (size_t)(i0 + q) * WP + j;
                #pragma unroll
                for (int r = 0; r < 4; ++r) {
                    const int o = c * 4 + r;
                    ob[(size_t)o * HP * WP]        = acc0[r];
                    ob[(size_t)(o + 16) * HP * WP] = acc1[r];
                }
            }
        }
    }
}

extern "C" void kernel_launch(void* const* d_in, const int* in_sizes, int n_in,
                              void* d_out, int out_size, void* d_ws, size_t ws_size,
                              hipStream_t stream)
{
    const float* x    = (const float*)d_in[0];
    const float* kern = (const float*)d_in[1];
    const float* pts  = (const float*)d_in[2];
    float* out = (float*)d_out;

    dim3 block(256, 1, 1);
    // 16 row-tiles of RB=4 (tile 15 clamps to i0=58), grouped 4 per block
    dim3 grid(WW / TC, 4, BS);   // 8 x 4 x 16 = 512 blocks
    flex_conv_pipe<<<grid, block, 0, stream>>>(x, kern, pts, out);
}